// Round 3
// baseline (2809.899 us; speedup 1.0000x reference)
//
#include <hip/hip_runtime.h>
#include <math.h>

#define TC 64           // time chunk
#define T_TOTAL 512
#define BATCH 512
#define D_IN 300
#define H1 128
#define G1 512          // 4*H1
#define H2 32
#define G2 128          // 4*H2
#define NCLS 14
#define KP1 320         // D_IN padded to mult of 32

typedef __attribute__((ext_vector_type(8))) __bf16 bf16x8;
typedef __attribute__((ext_vector_type(4))) float f32x4;

__device__ __forceinline__ float sigmoid_f(float x) {
    return __fdividef(1.0f, 1.0f + __expf(-x));
}
__device__ __forceinline__ float tanh_f(float x) {
    float xc = fminf(fmaxf(x, -15.f), 15.f);
    float e = __expf(2.0f * xc);
    return __fdividef(e - 1.0f, e + 1.0f);
}
__device__ __forceinline__ unsigned short f2bf(float x) {
    unsigned int u = __float_as_uint(x);
    unsigned int r = u + 0x7fffu + ((u >> 16) & 1u);
    return (unsigned short)(r >> 16);
}
__device__ __forceinline__ float bf2f(unsigned short h) {
    return __uint_as_float(((unsigned int)h) << 16);
}

// ---------------------------------------------------------------------------
// MFMA GEMM, bf16 hi/lo split (3 products, fp32 accum):
//   C[M,N] = A[M,K] @ B[K,N] + bias[N]
// ---------------------------------------------------------------------------
__global__ __launch_bounds__(256, 2)
void gemm_mfma_bias(const float* __restrict__ A, long rowStride, long rowBlockStride,
                    const unsigned short* __restrict__ BT, long bplane,
                    const float* __restrict__ bias, float* __restrict__ C,
                    int N, int K, int Kp)
{
    __shared__ unsigned short As[2][128][40];   // [hi/lo][row][k]

    const int tid = threadIdx.x;
    const int l   = tid & 63;
    const int w   = tid >> 6;
    const int wm  = w >> 1, wn = w & 1;
    const int m0  = blockIdx.y * 128;
    const int n0  = blockIdx.x * 128;

    const int srow = tid >> 1;
    const int skb  = (tid & 1) * 16;
    const long mg  = m0 + srow;
    const float* Arow = A + (mg >> 6) * rowBlockStride + (mg & 63) * rowStride;

    const int lr   = l & 15;
    const int koff = (l >> 4) * 8;

    f32x4 acc[4][4];
#pragma unroll
    for (int i = 0; i < 4; i++)
#pragma unroll
        for (int j = 0; j < 4; j++)
            acc[i][j] = (f32x4){0.f, 0.f, 0.f, 0.f};

    for (int k0 = 0; k0 < Kp; k0 += 32) {
#pragma unroll
        for (int i = 0; i < 4; i++) {
            int kg = k0 + skb + i * 4;
            float4 v = {0.f, 0.f, 0.f, 0.f};
            if (kg + 3 < K) {
                v = *(const float4*)(Arow + kg);
            } else {
                if (kg + 0 < K) v.x = Arow[kg + 0];
                if (kg + 1 < K) v.y = Arow[kg + 1];
                if (kg + 2 < K) v.z = Arow[kg + 2];
                if (kg + 3 < K) v.w = Arow[kg + 3];
            }
            ushort4 hi, lo;
            hi.x = f2bf(v.x); lo.x = f2bf(v.x - bf2f(hi.x));
            hi.y = f2bf(v.y); lo.y = f2bf(v.y - bf2f(hi.y));
            hi.z = f2bf(v.z); lo.z = f2bf(v.z - bf2f(hi.z));
            hi.w = f2bf(v.w); lo.w = f2bf(v.w - bf2f(hi.w));
            *(ushort4*)&As[0][srow][skb + i * 4] = hi;
            *(ushort4*)&As[1][srow][skb + i * 4] = lo;
        }
        __syncthreads();

        bf16x8 bh[4], bl[4];
#pragma unroll
        for (int fj = 0; fj < 4; fj++) {
            const unsigned short* bp = BT + (long)(n0 + wn * 64 + fj * 16 + lr) * Kp + k0 + koff;
            bh[fj] = *(const bf16x8*)bp;
            bl[fj] = *(const bf16x8*)(bp + bplane);
        }

#pragma unroll
        for (int fi = 0; fi < 4; fi++) {
            int ar = wm * 64 + fi * 16 + lr;
            bf16x8 ah = *(const bf16x8*)&As[0][ar][koff];
            bf16x8 al = *(const bf16x8*)&As[1][ar][koff];
#pragma unroll
            for (int fj = 0; fj < 4; fj++) {
                acc[fi][fj] = __builtin_amdgcn_mfma_f32_16x16x32_bf16(ah, bh[fj], acc[fi][fj], 0, 0, 0);
                acc[fi][fj] = __builtin_amdgcn_mfma_f32_16x16x32_bf16(ah, bl[fj], acc[fi][fj], 0, 0, 0);
                acc[fi][fj] = __builtin_amdgcn_mfma_f32_16x16x32_bf16(al, bh[fj], acc[fi][fj], 0, 0, 0);
            }
        }
        __syncthreads();
    }

#pragma unroll
    for (int fj = 0; fj < 4; fj++) {
        int col = n0 + wn * 64 + fj * 16 + lr;
        float bv = bias[col];
#pragma unroll
        for (int fi = 0; fi < 4; fi++) {
            int row = m0 + wm * 64 + fi * 16 + (l >> 4) * 4;
#pragma unroll
            for (int r = 0; r < 4; r++)
                C[(long)(row + r) * N + col] = acc[fi][fj][r] + bv;
        }
    }
}

// ---------------------------------------------------------------------------
// Prep: U1 -> bf16 hi/lo planes [2][512][128]; U2 -> U2T fp32;
// W1^T/W2^T -> bf16 hi/lo planes.
// ---------------------------------------------------------------------------
__global__ void prep_weights(const float* __restrict__ U1, unsigned short* __restrict__ U1bf,
                             const float* __restrict__ U2, float* __restrict__ U2T,
                             const float* __restrict__ W1, unsigned short* __restrict__ W1T,
                             const float* __restrict__ W2, unsigned short* __restrict__ W2T)
{
    int idx = blockIdx.x * 256 + threadIdx.x;
    if (idx < 512 * 128) {
        int j = idx / 128, k = idx % 128;     // j: gate col, k: h index
        float v = U1[k * 512 + j];
        unsigned short hi = f2bf(v);
        unsigned short lo = f2bf(v - bf2f(hi));
        U1bf[j * 128 + k] = hi;
        U1bf[512 * 128 + j * 128 + k] = lo;
    }
    if (idx < 32 * 128) {
        int k = idx / 128, j = idx % 128;
        U2T[j * 32 + k] = U2[idx];
    }
    if (idx < 512 * KP1) {
        int j = idx / KP1, k = idx % KP1;
        float v = (k < D_IN) ? W1[k * G1 + j] : 0.f;
        unsigned short hi = f2bf(v);
        unsigned short lo = f2bf(v - bf2f(hi));
        W1T[j * KP1 + k] = hi;
        W1T[512 * KP1 + j * KP1 + k] = lo;
    }
    if (idx < 128 * 128) {
        int j = idx / 128, k = idx % 128;
        float v = W2[k * G2 + j];
        unsigned short hi = f2bf(v);
        unsigned short lo = f2bf(v - bf2f(hi));
        W2T[j * 128 + k] = hi;
        W2T[128 * 128 + j * 128 + k] = lo;
    }
}

// ---------------------------------------------------------------------------
// LSTM1 MFMA scan. 32 WGs x 512 threads. WG owns 16 batch rows; wave w owns
// gate cols [64w, 64w+64). U1 (bf16 hi/lo) lives in VGPRs as B-fragments.
// h kept in LDS as XOR-swizzled bf16 hi/lo A-tiles; c in updater registers.
// 3-MFMA hi/lo split per product => fp32-grade accuracy on the matrix pipe.
// ---------------------------------------------------------------------------
__global__ __launch_bounds__(512, 2)
void lstm1_mfma(const float* __restrict__ xz,            // [B][TC][512]
                const unsigned short* __restrict__ U1bf, // [2][512][128]
                float* __restrict__ h1out,               // [B][TC][128]
                float* __restrict__ stateH,              // [B][128]
                float* __restrict__ stateC,              // [B][128]
                int firstChunk)
{
    const int tid = threadIdx.x;
    const int l   = tid & 63;
    const int w   = tid >> 6;          // wave 0..7
    const int lr  = l & 15;
    const int q   = l >> 4;            // quarter-wave 0..3
    const int koff = q * 8;
    const int qrow = q * 4;
    const int b0  = blockIdx.x * 16;

    __shared__ __align__(16) unsigned short Ah[16][128];
    __shared__ __align__(16) unsigned short Al[16][128];
    __shared__ __align__(16) float glds[16][516];        // padded: 2-way banks

    // ---- U1 B-fragments into registers (hi & lo planes) ----
    bf16x8 bh[4][4], bl[4][4];
#pragma unroll
    for (int nt = 0; nt < 4; nt++)
#pragma unroll
        for (int kt = 0; kt < 4; kt++) {
            const unsigned short* up = U1bf + (long)(w * 64 + nt * 16 + lr) * 128 + kt * 32 + koff;
            bh[nt][kt] = *(const bf16x8*)up;
            bl[nt][kt] = *(const bf16x8*)(up + 512 * 128);
        }

    // ---- updater mapping: thread -> (cn, rows rb+4rr) ----
    const int cn = tid & 127;
    const int rb = tid >> 7;           // 0..3
    float cst[4] = {0.f, 0.f, 0.f, 0.f};

    // ---- init h tiles (and c) ----
#pragma unroll
    for (int rr = 0; rr < 4; rr++) {
        int row = rb + rr * 4;
        float h = 0.f;
        if (!firstChunk) {
            h = stateH[(long)(b0 + row) * 128 + cn];
            cst[rr] = stateC[(long)(b0 + row) * 128 + cn];
        }
        unsigned short hi = f2bf(h);
        unsigned short lo = f2bf(h - bf2f(hi));
        int kidx = (((cn >> 3) ^ row) << 3) + (cn & 7);
        Ah[row][kidx] = hi;
        Al[row][kidx] = lo;
    }
    __syncthreads();

    // ---- xz prefetch base ----
    const float* xp = xz + (long)(b0 + qrow) * TC * 512 + w * 64 + lr;
    float xc[16], xn[16];
#pragma unroll
    for (int r = 0; r < 4; r++)
#pragma unroll
        for (int nt = 0; nt < 4; nt++)
            xc[nt * 4 + r] = xp[((long)r * TC + 0) * 512 + nt * 16];

    const bool use_tanh = ((w >> 1) == 2);

    for (int t = 0; t < TC; t++) {
        // A-fragments (swizzled LDS read, conflict-free)
        bf16x8 ah[4], al[4];
#pragma unroll
        for (int kt = 0; kt < 4; kt++) {
            int g = kt * 4 + q;
            ah[kt] = *(const bf16x8*)&Ah[lr][(g ^ lr) << 3];
            al[kt] = *(const bf16x8*)&Al[lr][(g ^ lr) << 3];
        }

        // prefetch next step's xz
        if (t + 1 < TC) {
#pragma unroll
            for (int r = 0; r < 4; r++)
#pragma unroll
                for (int nt = 0; nt < 4; nt++)
                    xn[nt * 4 + r] = xp[((long)r * TC + (t + 1)) * 512 + nt * 16];
        }

        // recurrence MFMAs: z_rec = h @ U (3-product hi/lo)
        f32x4 acc[4];
#pragma unroll
        for (int nt = 0; nt < 4; nt++)
            acc[nt] = (f32x4){0.f, 0.f, 0.f, 0.f};
#pragma unroll
        for (int kt = 0; kt < 4; kt++)
#pragma unroll
            for (int nt = 0; nt < 4; nt++) {
                acc[nt] = __builtin_amdgcn_mfma_f32_16x16x32_bf16(ah[kt], bh[nt][kt], acc[nt], 0, 0, 0);
                acc[nt] = __builtin_amdgcn_mfma_f32_16x16x32_bf16(ah[kt], bl[nt][kt], acc[nt], 0, 0, 0);
                acc[nt] = __builtin_amdgcn_mfma_f32_16x16x32_bf16(al[kt], bh[nt][kt], acc[nt], 0, 0, 0);
            }

        // z = z_rec + xz; activate; exchange via LDS
#pragma unroll
        for (int nt = 0; nt < 4; nt++)
#pragma unroll
            for (int r = 0; r < 4; r++) {
                float z = acc[nt][r] + xc[nt * 4 + r];
                glds[qrow + r][w * 64 + nt * 16 + lr] = use_tanh ? tanh_f(z) : sigmoid_f(z);
            }
        __syncthreads();

        // c/h update: thread (cn, rows rb+4rr)
#pragma unroll
        for (int rr = 0; rr < 4; rr++) {
            int row = rb + rr * 4;
            float iv = glds[row][cn];
            float fv = glds[row][128 + cn];
            float gv = glds[row][256 + cn];
            float ov = glds[row][384 + cn];
            cst[rr] = fv * cst[rr] + iv * gv;
            float h = ov * tanh_f(cst[rr]);
            h1out[((long)(b0 + row) * TC + t) * 128 + cn] = h;
            unsigned short hi = f2bf(h);
            unsigned short lo = f2bf(h - bf2f(hi));
            int kidx = (((cn >> 3) ^ row) << 3) + (cn & 7);
            Ah[row][kidx] = hi;
            Al[row][kidx] = lo;
            if (t == TC - 1) {
                stateH[(long)(b0 + row) * 128 + cn] = h;
                stateC[(long)(b0 + row) * 128 + cn] = cst[rr];
            }
        }
        __syncthreads();

#pragma unroll
        for (int i = 0; i < 16; i++) xc[i] = xn[i];
    }
}

// ---------------------------------------------------------------------------
// LSTM2 scan over one T-chunk. 256 WGs x 128 threads; 2 batch rows per WG.
// ---------------------------------------------------------------------------
__global__ __launch_bounds__(128)
void lstm2_scan(const float* __restrict__ xz2,    // [B][TC][128]
                const float* __restrict__ U2T,    // [128][32]
                float* __restrict__ stateH,       // [B][32]
                float* __restrict__ stateC,       // [B][32]
                int firstChunk)
{
    const int j  = threadIdx.x;        // 0..127
    const int b0 = blockIdx.x * 2;

    __shared__ __align__(16) float hs[2][32];
    __shared__ __align__(16) float gs[2][128];

    float U[32];
#pragma unroll
    for (int k = 0; k < 32; k += 4)
        *(float4*)&U[k] = *(const float4*)&U2T[j * 32 + k];

    const int cb = j >> 5;
    const int cn = j & 31;
    float creg = 0.f, hreg = 0.f;
    if (j < 64) {
        if (firstChunk) {
            hs[cb][cn] = 0.f;
        } else {
            hs[cb][cn] = stateH[(b0 + cb) * 32 + cn];
            creg       = stateC[(b0 + cb) * 32 + cn];
        }
    }
    __syncthreads();

    const float* xzp0 = xz2 + ((long)b0 * TC) * 128 + j;
    const float* xzp1 = xz2 + ((long)(b0 + 1) * TC) * 128 + j;
    float x0 = xzp0[0], x1 = xzp1[0];

    const bool is_g = (j >= 64) && (j < 96);

    for (int t = 0; t < TC; t++) {
        float xn0 = 0.f, xn1 = 0.f;
        if (t + 1 < TC) { xn0 = xzp0[(t + 1) * 128]; xn1 = xzp1[(t + 1) * 128]; }

        float a0 = x0, a1 = x1;
#pragma unroll
        for (int k = 0; k < 32; k += 4) {
            float4 h0 = *(const float4*)&hs[0][k];
            float4 h1 = *(const float4*)&hs[1][k];
            a0 += h0.x * U[k];     a0 += h0.y * U[k + 1];
            a0 += h0.z * U[k + 2]; a0 += h0.w * U[k + 3];
            a1 += h1.x * U[k];     a1 += h1.y * U[k + 1];
            a1 += h1.z * U[k + 2]; a1 += h1.w * U[k + 3];
        }

        float g0 = is_g ? tanh_f(a0) : sigmoid_f(a0);
        float g1 = is_g ? tanh_f(a1) : sigmoid_f(a1);
        gs[0][j] = g0;
        gs[1][j] = g1;
        __syncthreads();

        if (j < 64) {
            float iv = gs[cb][cn];
            float fv = gs[cb][32 + cn];
            float gv = gs[cb][64 + cn];
            float ov = gs[cb][96 + cn];
            creg = fv * creg + iv * gv;
            hreg = ov * tanh_f(creg);
            hs[cb][cn] = hreg;
        }
        __syncthreads();

        x0 = xn0; x1 = xn1;
    }

    if (j < 64) {
        stateH[(b0 + cb) * 32 + cn] = hreg;
        stateC[(b0 + cb) * 32 + cn] = creg;
    }
}

// ---------------------------------------------------------------------------
// Head: out = softmax(h2_last @ Wd + bd)
// ---------------------------------------------------------------------------
__global__ __launch_bounds__(256)
void head_kernel(const float* __restrict__ h2, const float* __restrict__ Wd,
                 const float* __restrict__ bd, float* __restrict__ out)
{
    int b = blockIdx.x * 256 + threadIdx.x;
    float h[H2];
#pragma unroll
    for (int k = 0; k < H2; k += 4)
        *(float4*)&h[k] = *(const float4*)&h2[b * H2 + k];

    float lg[NCLS];
#pragma unroll
    for (int c = 0; c < NCLS; c++) lg[c] = bd[c];
#pragma unroll
    for (int k = 0; k < H2; k++) {
        float hv = h[k];
#pragma unroll
        for (int c = 0; c < NCLS; c++)
            lg[c] += hv * Wd[k * NCLS + c];
    }
    float m = lg[0];
#pragma unroll
    for (int c = 1; c < NCLS; c++) m = fmaxf(m, lg[c]);
    float s = 0.f;
#pragma unroll
    for (int c = 0; c < NCLS; c++) { lg[c] = __expf(lg[c] - m); s += lg[c]; }
    float inv = __fdividef(1.0f, s);
#pragma unroll
    for (int c = 0; c < NCLS; c++) out[b * NCLS + c] = lg[c] * inv;
}

// ---------------------------------------------------------------------------
extern "C" void kernel_launch(void* const* d_in, const int* in_sizes, int n_in,
                              void* d_out, int out_size, void* d_ws, size_t ws_size,
                              hipStream_t stream)
{
    const float* x  = (const float*)d_in[0];
    const float* W1 = (const float*)d_in[1];
    const float* U1 = (const float*)d_in[2];
    const float* b1 = (const float*)d_in[3];
    const float* W2 = (const float*)d_in[4];
    const float* U2 = (const float*)d_in[5];
    const float* b2 = (const float*)d_in[6];
    const float* Wd = (const float*)d_in[7];
    const float* bd = (const float*)d_in[8];
    float* out = (float*)d_out;

    char* ws = (char*)d_ws;
    float* xz1 = (float*)(ws);                       // 67108864
    float* h1c = (float*)(ws + 67108864);            // 16777216
    float* xz2 = (float*)(ws + 83886080);            // 16777216
    float* s1h = (float*)(ws + 100663296);           // 262144
    float* s1c = (float*)(ws + 100925440);           // 262144
    float* s2h = (float*)(ws + 101187584);           // 65536
    float* s2c = (float*)(ws + 101253120);           // 65536
    unsigned short* U1bf = (unsigned short*)(ws + 101318656); // 2*512*128*2 = 262144
    float* U2T = (float*)(ws + 101580800);           // 16384
    unsigned short* W1T = (unsigned short*)(ws + 101597184);  // 655360
    unsigned short* W2T = (unsigned short*)(ws + 102252544);  // 65536

    prep_weights<<<640, 256, 0, stream>>>(U1, U1bf, U2, U2T, W1, W1T, W2, W2T);

    for (int c = 0; c < T_TOTAL / TC; c++) {
        const float* xchunk = x + (long)c * TC * D_IN;
        gemm_mfma_bias<<<dim3(G1 / 128, (BATCH * TC) / 128), 256, 0, stream>>>(
            xchunk, (long)D_IN, (long)T_TOTAL * D_IN, W1T, (long)512 * KP1,
            b1, xz1, G1, D_IN, KP1);
        lstm1_mfma<<<BATCH / 16, 512, 0, stream>>>(xz1, U1bf, h1c, s1h, s1c, c == 0);
        gemm_mfma_bias<<<dim3(G2 / 128, (BATCH * TC) / 128), 256, 0, stream>>>(
            h1c, (long)H1, (long)TC * H1, W2T, (long)128 * 128,
            b2, xz2, G2, H1, H1);
        lstm2_scan<<<BATCH / 2, 128, 0, stream>>>(xz2, U2T, s2h, s2c, c == 0);
    }

    head_kernel<<<BATCH / 256, 256, 0, stream>>>(s2h, Wd, bd, out);
}

// Round 4
// 1614.490 us; speedup vs baseline: 1.7404x; 1.7404x over previous
//
#include <hip/hip_runtime.h>
#include <math.h>

#define TC 64
#define NC 8
#define BATCH 512
#define T_TOTAL 512
#define D_IN 300
#define KP1 320
#define H1 128
#define G1 512
#define H2 32
#define NCLS 14

typedef unsigned short u16;
typedef __attribute__((ext_vector_type(8))) __bf16 bf16x8;
typedef __attribute__((ext_vector_type(4))) float f32x4;

#if __has_builtin(__builtin_amdgcn_exp2f)
__device__ __forceinline__ float fexp2(float x) { return __builtin_amdgcn_exp2f(x); }
#else
__device__ __forceinline__ float fexp2(float x) { return __expf(0.69314718056f * x); }
#endif
#if __has_builtin(__builtin_amdgcn_rcpf)
__device__ __forceinline__ float frcp(float x) { return __builtin_amdgcn_rcpf(x); }
#else
__device__ __forceinline__ float frcp(float x) { return __fdividef(1.0f, x); }
#endif
__device__ __forceinline__ float sig_f(float x) { return frcp(1.0f + fexp2(-1.44269504f * x)); }
__device__ __forceinline__ float th_f(float x)  { return 1.0f - 2.0f * frcp(1.0f + fexp2(2.88539008f * x)); }

__device__ __forceinline__ u16 f2bf(float x) {
    unsigned int u = __float_as_uint(x);
    unsigned int r = u + 0x7fffu + ((u >> 16) & 1u);
    return (u16)(r >> 16);
}
__device__ __forceinline__ float bf2f(u16 h) {
    return __uint_as_float(((unsigned int)h) << 16);
}

// ---------------------------------------------------------------------------
// Prep: permuted-column bf16 hi/lo planes.
// lstm1 perm: p = w*64+nt*16+lr  <->  orig col = nt*128 + w*16 + lr   (w<8)
// lstm2 perm: p = w*64+nt*16+lr  <->  orig col = nt*32  + w*16 + lr   (w<2)
// ---------------------------------------------------------------------------
__global__ void prep_weights(const float* __restrict__ U1, u16* __restrict__ U1bf,
                             const float* __restrict__ U2, u16* __restrict__ U2bf,
                             const float* __restrict__ W1, u16* __restrict__ W1T,
                             const float* __restrict__ W2, u16* __restrict__ W2T,
                             const float* __restrict__ b1, float* __restrict__ b1p,
                             const float* __restrict__ b2, float* __restrict__ b2p)
{
    int idx = blockIdx.x * 256 + threadIdx.x;
    if (idx < 512 * 128) {
        int p = idx >> 7, k = idx & 127;
        int orig = ((p >> 4) & 3) * 128 + ((p >> 6) << 4) + (p & 15);
        float v = U1[k * 512 + orig];
        u16 hi = f2bf(v);
        U1bf[p * 128 + k] = hi;
        U1bf[65536 + p * 128 + k] = f2bf(v - bf2f(hi));
    }
    if (idx < 512 * 320) {
        int p = idx / 320, k = idx % 320;
        int orig = ((p >> 4) & 3) * 128 + ((p >> 6) << 4) + (p & 15);
        float v = (k < D_IN) ? W1[k * 512 + orig] : 0.f;
        u16 hi = f2bf(v);
        W1T[p * 320 + k] = hi;
        W1T[163840 + p * 320 + k] = f2bf(v - bf2f(hi));
    }
    if (idx < 128 * 128) {
        int p = idx >> 7, k = idx & 127;
        int orig = ((p >> 4) & 3) * 32 + ((p >> 6) << 4) + (p & 15);
        float v = W2[k * 128 + orig];
        u16 hi = f2bf(v);
        W2T[p * 128 + k] = hi;
        W2T[16384 + p * 128 + k] = f2bf(v - bf2f(hi));
    }
    if (idx < 128 * 32) {
        int p = idx >> 5, k = idx & 31;
        int orig = ((p >> 4) & 3) * 32 + ((p >> 6) << 4) + (p & 15);
        float v = U2[k * 128 + orig];
        u16 hi = f2bf(v);
        U2bf[p * 32 + k] = hi;
        U2bf[4096 + p * 32 + k] = f2bf(v - bf2f(hi));
    }
    if (idx < 512) {
        int orig = ((idx >> 4) & 3) * 128 + ((idx >> 6) << 4) + (idx & 15);
        b1p[idx] = b1[orig];
    }
    if (idx < 128) {
        int orig = ((idx >> 4) & 3) * 32 + ((idx >> 6) << 4) + (idx & 15);
        b2p[idx] = b2[orig];
    }
}

// ---------------------------------------------------------------------------
// Pre-split x [B*T][300] -> bf16 hi/lo planes [B*T][320]
// ---------------------------------------------------------------------------
__global__ void xsplit(const float* __restrict__ x, u16* __restrict__ xhi, u16* __restrict__ xlo)
{
    long gid = (long)blockIdx.x * 256 + threadIdx.x;
    if (gid >= 262144L * 80) return;
    int m = (int)(gid / 80);
    int k0 = (int)(gid % 80) * 4;
    const float* xr = x + (long)m * D_IN;
    float4 v = {0.f, 0.f, 0.f, 0.f};
    if (k0 + 3 < D_IN) {
        v = *(const float4*)(xr + k0);
    } else {
        if (k0 + 0 < D_IN) v.x = xr[k0 + 0];
        if (k0 + 1 < D_IN) v.y = xr[k0 + 1];
        if (k0 + 2 < D_IN) v.z = xr[k0 + 2];
        if (k0 + 3 < D_IN) v.w = xr[k0 + 3];
    }
    ushort4 hi, lo;
    hi.x = f2bf(v.x); lo.x = f2bf(v.x - bf2f(hi.x));
    hi.y = f2bf(v.y); lo.y = f2bf(v.y - bf2f(hi.y));
    hi.z = f2bf(v.z); lo.z = f2bf(v.z - bf2f(hi.z));
    hi.w = f2bf(v.w); lo.w = f2bf(v.w - bf2f(hi.w));
    *(ushort4*)(xhi + (long)m * KP1 + k0) = hi;
    *(ushort4*)(xlo + (long)m * KP1 + k0) = lo;
}

// ---------------------------------------------------------------------------
// LDS-free frag-direct GEMM tile (128x128), 8 waves (2x4), wave = 64x32.
// A,B pre-split bf16 hi/lo planes [row][NK*32]; 3-product hi/lo split.
// XMAP: A row m (local b*TC+t) -> global x-plane row b*512 + chunk*TC + t.
// ---------------------------------------------------------------------------
template<int NK, bool XMAP>
__device__ __forceinline__ void gemm_tile(
    const u16* __restrict__ Ahi, const u16* __restrict__ Alo,
    const u16* __restrict__ Bhi, const u16* __restrict__ Blo,
    const float* __restrict__ bias, float* __restrict__ C,
    int Nc, int m0, int n0, int chunk)
{
    const int tid = threadIdx.x;
    const int l = tid & 63, w = tid >> 6;
    const int wm = w >> 2, wn = w & 3;
    const int lr = l & 15, q = l >> 4;
    const int koff = q * 8;
    const int LDA = NK * 32;

    const u16 *ah_p[4], *al_p[4];
#pragma unroll
    for (int fi = 0; fi < 4; fi++) {
        int mr = m0 + wm * 64 + fi * 16 + lr;
        long mg = XMAP ? ((long)(mr >> 6) * T_TOTAL + (long)chunk * TC + (mr & 63)) : (long)mr;
        ah_p[fi] = Ahi + mg * LDA + koff;
        al_p[fi] = Alo + mg * LDA + koff;
    }
    const u16 *bh_p[2], *bl_p[2];
    float bv[2];
#pragma unroll
    for (int fj = 0; fj < 2; fj++) {
        int nc = n0 + wn * 32 + fj * 16 + lr;
        bh_p[fj] = Bhi + (long)nc * LDA + koff;
        bl_p[fj] = Blo + (long)nc * LDA + koff;
        bv[fj] = bias[nc];
    }
    f32x4 acc[4][2];
#pragma unroll
    for (int fi = 0; fi < 4; fi++)
#pragma unroll
        for (int fj = 0; fj < 2; fj++)
            acc[fi][fj] = (f32x4){bv[fj], bv[fj], bv[fj], bv[fj]};

#pragma unroll
    for (int ks = 0; ks < NK; ks++) {
        bf16x8 a_h[4], a_l[4], b_h[2], b_l[2];
#pragma unroll
        for (int fj = 0; fj < 2; fj++) {
            b_h[fj] = *(const bf16x8*)(bh_p[fj] + ks * 32);
            b_l[fj] = *(const bf16x8*)(bl_p[fj] + ks * 32);
        }
#pragma unroll
        for (int fi = 0; fi < 4; fi++) {
            a_h[fi] = *(const bf16x8*)(ah_p[fi] + ks * 32);
            a_l[fi] = *(const bf16x8*)(al_p[fi] + ks * 32);
        }
#pragma unroll
        for (int fi = 0; fi < 4; fi++)
#pragma unroll
            for (int fj = 0; fj < 2; fj++) {
                acc[fi][fj] = __builtin_amdgcn_mfma_f32_16x16x32_bf16(a_h[fi], b_h[fj], acc[fi][fj], 0, 0, 0);
                acc[fi][fj] = __builtin_amdgcn_mfma_f32_16x16x32_bf16(a_h[fi], b_l[fj], acc[fi][fj], 0, 0, 0);
                acc[fi][fj] = __builtin_amdgcn_mfma_f32_16x16x32_bf16(a_l[fi], b_h[fj], acc[fi][fj], 0, 0, 0);
            }
    }
#pragma unroll
    for (int fi = 0; fi < 4; fi++)
#pragma unroll
        for (int fj = 0; fj < 2; fj++) {
            int col = n0 + wn * 32 + fj * 16 + lr;
            int rb_ = m0 + wm * 64 + fi * 16 + q * 4;
#pragma unroll
            for (int rr = 0; rr < 4; rr++)
                C[(long)(rb_ + rr) * Nc + col] = acc[fi][fj][rr];
        }
}

// ---------------------------------------------------------------------------
// Role A: lstm1 scan, gate-permuted. WG owns 16 batch rows; wave w owns the
// 4 gates of h-cols w*16..w*16+15. In-register update; 1 barrier/step;
// double-buffered XOR-swizzled h LDS tiles; h emitted as bf16 hi/lo planes.
// ---------------------------------------------------------------------------
static __device__ __forceinline__ void lstm1_role(
    const float* __restrict__ xz, const u16* __restrict__ U1bf,
    u16* __restrict__ h1hi, u16* __restrict__ h1lo,
    float* __restrict__ s1h, float* __restrict__ s1c, int first, u16* sm)
{
    const int tid = threadIdx.x;
    const int l = tid & 63, w = tid >> 6;
    const int lr = l & 15, q = l >> 4;
    const int koff = q * 8;
    const int cn = w * 16 + lr;
    const int b0 = blockIdx.x * 16;

    u16* Ah = sm;          // [2][16][128]
    u16* Al = sm + 4096;

    bf16x8 bh[4][4], bl[4][4];
#pragma unroll
    for (int nt = 0; nt < 4; nt++)
#pragma unroll
        for (int kt = 0; kt < 4; kt++) {
            const u16* up = U1bf + (long)(w * 64 + nt * 16 + lr) * 128 + kt * 32 + koff;
            bh[nt][kt] = *(const bf16x8*)up;
            bl[nt][kt] = *(const bf16x8*)(up + 65536);
        }

    float cst[4];
#pragma unroll
    for (int r = 0; r < 4; r++) {
        int rw = q * 4 + r;
        float h = 0.f;
        cst[r] = 0.f;
        if (!first) {
            h = s1h[(long)(b0 + rw) * 128 + cn];
            cst[r] = s1c[(long)(b0 + rw) * 128 + cn];
        }
        u16 hi = f2bf(h), lo = f2bf(h - bf2f(hi));
        int idx = (((cn >> 3) ^ rw) << 3) + (cn & 7);
        Ah[rw * 128 + idx] = hi;
        Al[rw * 128 + idx] = lo;
    }
    __syncthreads();

    const float* xb[4];
#pragma unroll
    for (int r = 0; r < 4; r++)
        xb[r] = xz + (long)(b0 + q * 4 + r) * TC * 512 + w * 64 + lr;

    float xc[16];
#pragma unroll
    for (int nt = 0; nt < 4; nt++)
#pragma unroll
        for (int r = 0; r < 4; r++)
            xc[nt * 4 + r] = xb[r][nt * 16];

    int pb = 0;
    for (int t = 0; t < TC; t++) {
        bf16x8 ah[4], al[4];
#pragma unroll
        for (int kt = 0; kt < 4; kt++) {
            int phys = (((kt * 4 + q) ^ lr) << 3);
            ah[kt] = *(const bf16x8*)&Ah[pb * 2048 + lr * 128 + phys];
            al[kt] = *(const bf16x8*)&Al[pb * 2048 + lr * 128 + phys];
        }
        float xn[16];
        if (t + 1 < TC) {
            int to = (t + 1) * 512;
#pragma unroll
            for (int nt = 0; nt < 4; nt++)
#pragma unroll
                for (int r = 0; r < 4; r++)
                    xn[nt * 4 + r] = xb[r][to + nt * 16];
        }
        f32x4 acc[4];
#pragma unroll
        for (int nt = 0; nt < 4; nt++)
            acc[nt] = (f32x4){xc[nt * 4 + 0], xc[nt * 4 + 1], xc[nt * 4 + 2], xc[nt * 4 + 3]};
#pragma unroll
        for (int kt = 0; kt < 4; kt++)
#pragma unroll
            for (int nt = 0; nt < 4; nt++) {
                acc[nt] = __builtin_amdgcn_mfma_f32_16x16x32_bf16(ah[kt], bh[nt][kt], acc[nt], 0, 0, 0);
                acc[nt] = __builtin_amdgcn_mfma_f32_16x16x32_bf16(ah[kt], bl[nt][kt], acc[nt], 0, 0, 0);
                acc[nt] = __builtin_amdgcn_mfma_f32_16x16x32_bf16(al[kt], bh[nt][kt], acc[nt], 0, 0, 0);
            }
#pragma unroll
        for (int r = 0; r < 4; r++) {
            float iv = sig_f(acc[0][r]);
            float fv = sig_f(acc[1][r]);
            float gv = th_f(acc[2][r]);
            float ov = sig_f(acc[3][r]);
            cst[r] = fv * cst[r] + iv * gv;
            float h = ov * th_f(cst[r]);
            u16 hi = f2bf(h), lo = f2bf(h - bf2f(hi));
            int rw = q * 4 + r;
            int idx = (((cn >> 3) ^ rw) << 3) + (cn & 7);
            Ah[(pb ^ 1) * 2048 + rw * 128 + idx] = hi;
            Al[(pb ^ 1) * 2048 + rw * 128 + idx] = lo;
            long gm = ((long)(b0 + rw) * TC + t) * 128 + cn;
            h1hi[gm] = hi;
            h1lo[gm] = lo;
            if (t == TC - 1) {
                s1h[(long)(b0 + rw) * 128 + cn] = h;
                s1c[(long)(b0 + rw) * 128 + cn] = cst[r];
            }
        }
        __syncthreads();
        pb ^= 1;
        if (t + 1 < TC) {
#pragma unroll
            for (int i = 0; i < 16; i++) xc[i] = xn[i];
        }
    }
}

// ---------------------------------------------------------------------------
// Role B: lstm2 scan (gate-permuted), 16 rows/WG, waves 0-1 active.
// ---------------------------------------------------------------------------
static __device__ __forceinline__ void lstm2_role(
    const float* __restrict__ xz2, const u16* __restrict__ U2bf,
    float* __restrict__ s2h, float* __restrict__ s2c, int first, u16* sm)
{
    const int tid = threadIdx.x;
    const int b0 = (blockIdx.x - 32) * 16;
    const bool act = tid < 128;
    const int l = tid & 63, w = (tid >> 6) & 1;
    const int lr = l & 15, q = l >> 4;
    const int koff = q * 8;
    const int cn = w * 16 + lr;

    u16* Ah = sm;          // [2][16][40]
    u16* Al = sm + 1280;

    bf16x8 bh[4], bl[4];
    float cst[4] = {0.f, 0.f, 0.f, 0.f};
    const float* xb[4];
    float xc[16];

    if (act) {
#pragma unroll
        for (int nt = 0; nt < 4; nt++) {
            const u16* up = U2bf + (long)(w * 64 + nt * 16 + lr) * 32 + koff;
            bh[nt] = *(const bf16x8*)up;
            bl[nt] = *(const bf16x8*)(up + 4096);
        }
#pragma unroll
        for (int r = 0; r < 4; r++) {
            int rw = q * 4 + r;
            float h = 0.f;
            if (!first) {
                h = s2h[(long)(b0 + rw) * 32 + cn];
                cst[r] = s2c[(long)(b0 + rw) * 32 + cn];
            }
            u16 hi = f2bf(h), lo = f2bf(h - bf2f(hi));
            Ah[rw * 40 + cn] = hi;
            Al[rw * 40 + cn] = lo;
        }
#pragma unroll
        for (int r = 0; r < 4; r++)
            xb[r] = xz2 + (long)(b0 + q * 4 + r) * TC * 128 + w * 64 + lr;
#pragma unroll
        for (int nt = 0; nt < 4; nt++)
#pragma unroll
            for (int r = 0; r < 4; r++)
                xc[nt * 4 + r] = xb[r][nt * 16];
    }
    __syncthreads();

    int pb = 0;
    for (int t = 0; t < TC; t++) {
        if (act) {
            bf16x8 ah = *(const bf16x8*)&Ah[pb * 640 + lr * 40 + koff];
            bf16x8 al = *(const bf16x8*)&Al[pb * 640 + lr * 40 + koff];
            float xn[16];
            if (t + 1 < TC) {
                int to = (t + 1) * 128;
#pragma unroll
                for (int nt = 0; nt < 4; nt++)
#pragma unroll
                    for (int r = 0; r < 4; r++)
                        xn[nt * 4 + r] = xb[r][to + nt * 16];
            }
            f32x4 acc[4];
#pragma unroll
            for (int nt = 0; nt < 4; nt++) {
                acc[nt] = (f32x4){xc[nt * 4 + 0], xc[nt * 4 + 1], xc[nt * 4 + 2], xc[nt * 4 + 3]};
                acc[nt] = __builtin_amdgcn_mfma_f32_16x16x32_bf16(ah, bh[nt], acc[nt], 0, 0, 0);
                acc[nt] = __builtin_amdgcn_mfma_f32_16x16x32_bf16(ah, bl[nt], acc[nt], 0, 0, 0);
                acc[nt] = __builtin_amdgcn_mfma_f32_16x16x32_bf16(al, bh[nt], acc[nt], 0, 0, 0);
            }
#pragma unroll
            for (int r = 0; r < 4; r++) {
                float iv = sig_f(acc[0][r]);
                float fv = sig_f(acc[1][r]);
                float gv = th_f(acc[2][r]);
                float ov = sig_f(acc[3][r]);
                cst[r] = fv * cst[r] + iv * gv;
                float h = ov * th_f(cst[r]);
                u16 hi = f2bf(h), lo = f2bf(h - bf2f(hi));
                int rw = q * 4 + r;
                Ah[(pb ^ 1) * 640 + rw * 40 + cn] = hi;
                Al[(pb ^ 1) * 640 + rw * 40 + cn] = lo;
                if (t == TC - 1) {
                    s2h[(long)(b0 + rw) * 32 + cn] = h;
                    s2c[(long)(b0 + rw) * 32 + cn] = cst[r];
                }
            }
            if (t + 1 < TC) {
#pragma unroll
                for (int i = 0; i < 16; i++) xc[i] = xn[i];
            }
        }
        __syncthreads();
        pb ^= 1;
    }
}

// ---------------------------------------------------------------------------
// Fused mega kernel: A = lstm1(cA) [WG 0-31], B = lstm2(cB) [WG 32-63],
// C = gemm1(g1) + gemm2(g2) persistent tile loop [remaining WGs].
// ---------------------------------------------------------------------------
__global__ __launch_bounds__(512, 2) void mega(
    const u16* __restrict__ xhi, const u16* __restrict__ xlo,
    const u16* __restrict__ W1Th, const u16* __restrict__ W1Tl, const float* __restrict__ b1p,
    const u16* __restrict__ W2Th, const u16* __restrict__ W2Tl, const float* __restrict__ b2p,
    const u16* __restrict__ U1bf, const u16* __restrict__ U2bf,
    float* xz1_0, float* xz1_1, float* xz2_0, float* xz2_1,
    u16* h1hi_0, u16* h1hi_1, u16* h1lo_0, u16* h1lo_1,
    float* s1h, float* s1c, float* s2h, float* s2c,
    int cA, int cB, int g1, int g2)
{
    __shared__ __align__(16) u16 sm[8192];
    int bid = blockIdx.x;

    if (cA >= 0 && bid < 32) {
        const float* xz = (cA & 1) ? xz1_1 : xz1_0;
        u16* hh = (cA & 1) ? h1hi_1 : h1hi_0;
        u16* hl = (cA & 1) ? h1lo_1 : h1lo_0;
        lstm1_role(xz, U1bf, hh, hl, s1h, s1c, cA == 0, sm);
        return;
    }
    if (cB >= 0 && bid >= 32 && bid < 64) {
        const float* xz2 = (cB & 1) ? xz2_1 : xz2_0;
        lstm2_role(xz2, U2bf, s2h, s2c, cB == 0, sm);
        return;
    }
    int cwid = bid, ncw = 256;
    if (cA >= 0) { ncw -= 32; cwid -= 32; }
    if (cB >= 0) { ncw -= 32; if (bid >= 64) cwid -= 32; }
    int ng1 = (g1 >= 0) ? 1024 : 0;
    int ng2 = (g2 >= 0) ? 256 : 0;
    float* xz1o = (g1 >= 0 && (g1 & 1)) ? xz1_1 : xz1_0;
    float* xz2o = (g2 >= 0 && (g2 & 1)) ? xz2_1 : xz2_0;
    const u16* hh = (g2 >= 0 && (g2 & 1)) ? h1hi_1 : h1hi_0;
    const u16* hl = (g2 >= 0 && (g2 & 1)) ? h1lo_1 : h1lo_0;
    for (int tile = cwid; tile < ng1 + ng2; tile += ncw) {
        if (tile < ng1)
            gemm_tile<10, true>(xhi, xlo, W1Th, W1Tl, b1p, xz1o, 512,
                                (tile >> 2) * 128, (tile & 3) * 128, g1);
        else
            gemm_tile<4, false>(hh, hl, W2Th, W2Tl, b2p, xz2o, 128,
                                (tile - ng1) * 128, 0, 0);
    }
}

// ---------------------------------------------------------------------------
// Head: out = softmax(h2_last @ Wd + bd)
// ---------------------------------------------------------------------------
__global__ __launch_bounds__(256)
void head_kernel(const float* __restrict__ h2, const float* __restrict__ Wd,
                 const float* __restrict__ bd, float* __restrict__ out)
{
    int b = blockIdx.x * 256 + threadIdx.x;
    float h[H2];
#pragma unroll
    for (int k = 0; k < H2; k += 4)
        *(float4*)&h[k] = *(const float4*)&h2[b * H2 + k];

    float lg[NCLS];
#pragma unroll
    for (int c = 0; c < NCLS; c++) lg[c] = bd[c];
#pragma unroll
    for (int k = 0; k < H2; k++) {
        float hv = h[k];
#pragma unroll
        for (int c = 0; c < NCLS; c++)
            lg[c] += hv * Wd[k * NCLS + c];
    }
    float m = lg[0];
#pragma unroll
    for (int c = 1; c < NCLS; c++) m = fmaxf(m, lg[c]);
    float s = 0.f;
#pragma unroll
    for (int c = 0; c < NCLS; c++) { lg[c] = __expf(lg[c] - m); s += lg[c]; }
    float inv = __fdividef(1.0f, s);
#pragma unroll
    for (int c = 0; c < NCLS; c++) out[b * NCLS + c] = lg[c] * inv;
}

// ---------------------------------------------------------------------------
extern "C" void kernel_launch(void* const* d_in, const int* in_sizes, int n_in,
                              void* d_out, int out_size, void* d_ws, size_t ws_size,
                              hipStream_t stream)
{
    const float* x  = (const float*)d_in[0];
    const float* W1 = (const float*)d_in[1];
    const float* U1 = (const float*)d_in[2];
    const float* b1 = (const float*)d_in[3];
    const float* W2 = (const float*)d_in[4];
    const float* U2 = (const float*)d_in[5];
    const float* b2 = (const float*)d_in[6];
    const float* Wd = (const float*)d_in[7];
    const float* bd = (const float*)d_in[8];
    float* out = (float*)d_out;

    char* ws = (char*)d_ws;
    float* xz1[2] = {(float*)(ws + 0L),         (float*)(ws + 67108864L)};
    u16* xhi      = (u16*)(ws + 134217728L);
    u16* xlo      = (u16*)(ws + 301989888L);
    u16* h1hi[2]  = {(u16*)(ws + 469762048L),   (u16*)(ws + 478150656L)};
    u16* h1lo[2]  = {(u16*)(ws + 486539264L),   (u16*)(ws + 494927872L)};
    float* xz2[2] = {(float*)(ws + 503316480L), (float*)(ws + 520093696L)};
    float* s1h    = (float*)(ws + 536870912L);
    float* s1c    = (float*)(ws + 537133056L);
    float* s2h    = (float*)(ws + 537395200L);
    float* s2c    = (float*)(ws + 537460736L);
    u16* U1bf     = (u16*)(ws + 537526272L);
    u16* U2bf     = (u16*)(ws + 537788416L);
    u16* W1T      = (u16*)(ws + 537804800L);
    u16* W2T      = (u16*)(ws + 538460160L);
    float* b1p    = (float*)(ws + 538525696L);
    float* b2p    = (float*)(ws + 538527744L);

    prep_weights<<<640, 256, 0, stream>>>(U1, U1bf, U2, U2bf, W1, W1T, W2, W2T,
                                          b1, b1p, b2, b2p);
    xsplit<<<81920, 256, 0, stream>>>(x, xhi, xlo);

#define MEGA(cA_, cB_, g1_, g2_) \
    mega<<<256, 512, 0, stream>>>(xhi, xlo, W1T, W1T + 163840, b1p, \
        W2T, W2T + 16384, b2p, U1bf, U2bf, \
        xz1[0], xz1[1], xz2[0], xz2[1], h1hi[0], h1hi[1], h1lo[0], h1lo[1], \
        s1h, s1c, s2h, s2c, cA_, cB_, g1_, g2_)

    MEGA(-1, -1, 0, -1);
    for (int c = 0; c < NC; c++)
        MEGA(c, (c >= 2) ? c - 2 : -1, (c + 1 < NC) ? c + 1 : -1, (c >= 1) ? c - 1 : -1);
    MEGA(-1, NC - 2, -1, NC - 1);
    MEGA(-1, NC - 1, -1, -1);
#undef MEGA

    head_kernel<<<2, 256, 0, stream>>>(s2h, Wd, bd, out);
}

// Round 6
// 1412.683 us; speedup vs baseline: 1.9891x; 1.1429x over previous
//
#include <hip/hip_runtime.h>
#include <math.h>

#define TC 64
#define NC 8
#define BATCH 512
#define T_TOTAL 512
#define D_IN 300
#define KP1 320
#define H1 128
#define G1 512
#define H2 32
#define NCLS 14

typedef unsigned short u16;
typedef __attribute__((ext_vector_type(8))) _Float16 f16x8;
typedef __attribute__((ext_vector_type(4))) float f32x4;

__device__ __forceinline__ float fexp2(float x) { return __builtin_amdgcn_exp2f(x); }
__device__ __forceinline__ float frcp(float x)  { return __builtin_amdgcn_rcpf(x); }
// sigmoid / tanh via exp2 + rcp (4-5 ops each)
__device__ __forceinline__ float sig_f(float x) { return frcp(1.0f + fexp2(-1.44269504f * x)); }
__device__ __forceinline__ float th_f(float x)  { return 1.0f - 2.0f * frcp(1.0f + fexp2(2.88539008f * x)); }

// LDS-only barrier: no vmcnt(0) drain (global loads/stores stay in flight)
__device__ __forceinline__ void lds_barrier() {
    asm volatile("s_waitcnt lgkmcnt(0)" ::: "memory");
    __builtin_amdgcn_s_barrier();
}

// ---------------------------------------------------------------------------
// Prep: permuted-column f16 planes (single plane, fp16 mantissa is enough:
// z-err ~1.4e-4/step vs 1.9e-3 threshold).
// lstm1 perm: p = w*64+nt*16+lr  <->  orig col = nt*128 + w*16 + lr   (w<8)
// lstm2 perm: p = w*64+nt*16+lr  <->  orig col = nt*32  + w*16 + lr   (w<2)
// ---------------------------------------------------------------------------
__global__ void prep_weights(const float* __restrict__ U1, _Float16* __restrict__ U1p,
                             const float* __restrict__ U2, _Float16* __restrict__ U2p,
                             const float* __restrict__ W1, _Float16* __restrict__ W1T,
                             const float* __restrict__ W2, _Float16* __restrict__ W2T,
                             const float* __restrict__ b1, float* __restrict__ b1p,
                             const float* __restrict__ b2, float* __restrict__ b2p)
{
    int idx = blockIdx.x * 256 + threadIdx.x;
    if (idx < 512 * 128) {
        int p = idx >> 7, k = idx & 127;
        int orig = ((p >> 4) & 3) * 128 + ((p >> 6) << 4) + (p & 15);
        U1p[p * 128 + k] = (_Float16)U1[k * 512 + orig];
    }
    if (idx < 512 * 320) {
        int p = idx / 320, k = idx % 320;
        int orig = ((p >> 4) & 3) * 128 + ((p >> 6) << 4) + (p & 15);
        W1T[p * 320 + k] = (_Float16)((k < D_IN) ? W1[k * 512 + orig] : 0.f);
    }
    if (idx < 128 * 128) {
        int p = idx >> 7, k = idx & 127;
        int orig = ((p >> 4) & 3) * 32 + ((p >> 6) << 4) + (p & 15);
        W2T[p * 128 + k] = (_Float16)W2[k * 128 + orig];
    }
    if (idx < 128 * 32) {
        int p = idx >> 5, k = idx & 31;
        int orig = ((p >> 4) & 3) * 32 + ((p >> 6) << 4) + (p & 15);
        U2p[p * 32 + k] = (_Float16)U2[k * 128 + orig];
    }
    if (idx < 512) {
        int orig = ((idx >> 4) & 3) * 128 + ((idx >> 6) << 4) + (idx & 15);
        b1p[idx] = b1[orig];
    }
    if (idx < 128) {
        int orig = ((idx >> 4) & 3) * 32 + ((idx >> 6) << 4) + (idx & 15);
        b2p[idx] = b2[orig];
    }
}

// ---------------------------------------------------------------------------
// x [B*T][300] f32 -> single f16 plane [B*T][320]; 8 elems/thread
// ---------------------------------------------------------------------------
__global__ void xsplit(const float* __restrict__ x, _Float16* __restrict__ xh)
{
    long gid = (long)blockIdx.x * 256 + threadIdx.x;
    if (gid >= 262144L * 40) return;
    int m  = (int)(gid / 40);
    int k0 = (int)(gid % 40) * 8;
    const float* xr = x + (long)m * D_IN;
    f16x8 o;
#pragma unroll
    for (int j = 0; j < 8; j++) {
        int k = k0 + j;
        o[j] = (_Float16)((k < D_IN) ? xr[k] : 0.f);
    }
    *(f16x8*)(xh + (long)m * KP1 + k0) = o;
}

// ---------------------------------------------------------------------------
// Frag-direct f16 GEMM tile (128x128), 8 waves (2x4), wave = 64x32.
// M-index m <-> (b,t): b = ((m>>8)<<2)|(m&3), t = (m>>2)&63  (b&3 minor so
// the D-fragment's 4 rows are b-consecutive -> float4 C store along b).
// C layout: [t][Nc][512b]. A row: XMAP ? b*512+chunk*64+t (x plane)
//                                      : b*64+t (h1 plane).
// ---------------------------------------------------------------------------
template<int NK, bool XMAP>
__device__ __forceinline__ void gemm_tile(
    const _Float16* __restrict__ A, const _Float16* __restrict__ B,
    const float* __restrict__ bias, float* __restrict__ C,
    int Nc, int m0, int n0, int chunk)
{
    const int tid = threadIdx.x;
    const int l = tid & 63, w = tid >> 6;
    const int wm = w >> 2, wn = w & 3;
    const int lr = l & 15, q = l >> 4;
    const int koff = q * 8;
    const int LDA = NK * 32;

    const _Float16* ap[4];
#pragma unroll
    for (int fi = 0; fi < 4; fi++) {
        int m = m0 + wm * 64 + fi * 16 + lr;
        int b = ((m >> 8) << 2) | (m & 3);
        int t = (m >> 2) & 63;
        long row = XMAP ? ((long)b * T_TOTAL + (long)chunk * TC + t)
                        : ((long)b * TC + t);
        ap[fi] = A + row * LDA + koff;
    }
    const _Float16* bp[2];
    float bv[2];
#pragma unroll
    for (int fj = 0; fj < 2; fj++) {
        int nc = n0 + wn * 32 + fj * 16 + lr;
        bp[fj] = B + (long)nc * LDA + koff;
        bv[fj] = bias[nc];
    }
    f32x4 acc[4][2];
#pragma unroll
    for (int fi = 0; fi < 4; fi++)
#pragma unroll
        for (int fj = 0; fj < 2; fj++)
            acc[fi][fj] = (f32x4){bv[fj], bv[fj], bv[fj], bv[fj]};

#pragma unroll
    for (int ks = 0; ks < NK; ks++) {
        f16x8 av[4], bvv[2];
#pragma unroll
        for (int fj = 0; fj < 2; fj++)
            bvv[fj] = *(const f16x8*)(bp[fj] + ks * 32);
#pragma unroll
        for (int fi = 0; fi < 4; fi++)
            av[fi] = *(const f16x8*)(ap[fi] + ks * 32);
#pragma unroll
        for (int fi = 0; fi < 4; fi++)
#pragma unroll
            for (int fj = 0; fj < 2; fj++)
                acc[fi][fj] = __builtin_amdgcn_mfma_f32_16x16x32_f16(av[fi], bvv[fj], acc[fi][fj], 0, 0, 0);
    }

#pragma unroll
    for (int fi = 0; fi < 4; fi++) {
        int mq = m0 + wm * 64 + fi * 16 + q * 4;
        int bb = (mq >> 8) << 2;
        int tt = (mq >> 2) & 63;
#pragma unroll
        for (int fj = 0; fj < 2; fj++) {
            int col = n0 + wn * 32 + fj * 16 + lr;
            *(float4*)(C + ((long)tt * Nc + col) * 512 + bb) =
                *(float4*)&acc[fi][fj];
        }
    }
}

// ---------------------------------------------------------------------------
// Role A: lstm1 scan, f16 single-product. WG owns 16 batch rows; wave w owns
// the 4 gates of h-cols w*16..w*16+15 (permuted layout). In-register c/h
// update; 1 LDS-only barrier/step; dbuf XOR-swizzled f16 h tile.
// xz layout [t][512p][512b] -> 4 float4 loads/step that ARE the MFMA C-init.
// ---------------------------------------------------------------------------
static __device__ __forceinline__ void lstm1_role(
    const float* __restrict__ xz, const _Float16* __restrict__ U1p,
    _Float16* __restrict__ h1f, float* __restrict__ s1h, float* __restrict__ s1c,
    int first, char* smc)
{
    const int tid = threadIdx.x;
    const int l = tid & 63, w = tid >> 6;
    const int lr = l & 15, q = l >> 4;
    const int koff = q * 8;
    const int cn = w * 16 + lr;
    const int b0 = blockIdx.x * 16;
    const int p0 = w * 64 + lr;
    const int bq = b0 + q * 4;

    _Float16* Ah = (_Float16*)smc;   // [2][16][128]

    f16x8 uh[4][4];
#pragma unroll
    for (int nt = 0; nt < 4; nt++)
#pragma unroll
        for (int kt = 0; kt < 4; kt++)
            uh[nt][kt] = *(const f16x8*)(U1p + (long)(w * 64 + nt * 16 + lr) * 128 + kt * 32 + koff);

    float cst[4];
#pragma unroll
    for (int r = 0; r < 4; r++) {
        int rw = q * 4 + r;
        float h = 0.f;
        cst[r] = 0.f;
        if (!first) {
            h = s1h[(long)(b0 + rw) * 128 + cn];
            cst[r] = s1c[(long)(b0 + rw) * 128 + cn];
        }
        int idx = (((cn >> 3) ^ rw) << 3) + (cn & 7);
        Ah[rw * 128 + idx] = (_Float16)h;
    }
    lds_barrier();

    float4 xc[4], xn[4];
#pragma unroll
    for (int nt = 0; nt < 4; nt++)
        xc[nt] = *(const float4*)&xz[((long)0 * 512 + p0 + nt * 16) * 512 + bq];

    auto step = [&](int T, int PB, float4* XC, float4* XN) {
        f16x8 ah[4];
#pragma unroll
        for (int kt = 0; kt < 4; kt++)
            ah[kt] = *(const f16x8*)&Ah[PB * 2048 + lr * 128 + ((((kt << 2) + q) ^ lr) << 3)];
        if (T + 1 < TC) {
#pragma unroll
            for (int nt = 0; nt < 4; nt++)
                XN[nt] = *(const float4*)&xz[((long)(T + 1) * 512 + p0 + nt * 16) * 512 + bq];
        }
        f32x4 acc[4];
#pragma unroll
        for (int nt = 0; nt < 4; nt++)
            acc[nt] = __builtin_bit_cast(f32x4, XC[nt]);
#pragma unroll
        for (int kt = 0; kt < 4; kt++)
#pragma unroll
            for (int nt = 0; nt < 4; nt++)
                acc[nt] = __builtin_amdgcn_mfma_f32_16x16x32_f16(ah[kt], uh[nt][kt], acc[nt], 0, 0, 0);
#pragma unroll
        for (int r = 0; r < 4; r++) {
            float iv = sig_f(acc[0][r]);
            float fv = sig_f(acc[1][r]);
            float gv = th_f(acc[2][r]);
            float ov = sig_f(acc[3][r]);
            cst[r] = fv * cst[r] + iv * gv;
            float h = ov * th_f(cst[r]);
            _Float16 hh = (_Float16)h;
            int rw = (q << 2) + r;
            int idx = (((cn >> 3) ^ rw) << 3) + (cn & 7);
            Ah[(PB ^ 1) * 2048 + rw * 128 + idx] = hh;
            h1f[((long)(b0 + rw) * TC + T) * 128 + cn] = hh;
            if (T == TC - 1) {
                s1h[(long)(b0 + rw) * 128 + cn] = h;
                s1c[(long)(b0 + rw) * 128 + cn] = cst[r];
            }
        }
        lds_barrier();
    };

    for (int t = 0; t < TC; t += 2) {
        step(t, 0, xc, xn);
        step(t + 1, 1, xn, xc);
    }
}

// ---------------------------------------------------------------------------
// Role B: lstm2 scan, f16 single-product, waves 0-1 active.
// xz2 layout [t][128p][512b].
// ---------------------------------------------------------------------------
static __device__ __forceinline__ void lstm2_role(
    const float* __restrict__ xz2, const _Float16* __restrict__ U2p,
    float* __restrict__ s2h, float* __restrict__ s2c, int first, char* smc)
{
    const int tid = threadIdx.x;
    const int b0 = (blockIdx.x - 32) * 16;
    const bool act = tid < 128;
    const int l = tid & 63, w = (tid >> 6) & 1;
    const int lr = l & 15, q = l >> 4;
    const int koff = q * 8;
    const int cn = w * 16 + lr;
    const int p0 = w * 64 + lr;
    const int bq = b0 + q * 4;

    _Float16* Ah = (_Float16*)smc;   // [2][16][40]

    f16x8 uh[4];
    float cst[4] = {0.f, 0.f, 0.f, 0.f};
    float4 xc[4], xn[4];

    if (act) {
#pragma unroll
        for (int nt = 0; nt < 4; nt++)
            uh[nt] = *(const f16x8*)(U2p + (long)(w * 64 + nt * 16 + lr) * 32 + koff);
#pragma unroll
        for (int r = 0; r < 4; r++) {
            int rw = q * 4 + r;
            float h = 0.f;
            if (!first) {
                h = s2h[(long)(b0 + rw) * 32 + cn];
                cst[r] = s2c[(long)(b0 + rw) * 32 + cn];
            }
            Ah[rw * 40 + cn] = (_Float16)h;
        }
#pragma unroll
        for (int nt = 0; nt < 4; nt++)
            xc[nt] = *(const float4*)&xz2[((long)0 * 128 + p0 + nt * 16) * 512 + bq];
    }
    lds_barrier();

    auto step = [&](int T, int PB, float4* XC, float4* XN) {
        if (act) {
            f16x8 ah = *(const f16x8*)&Ah[PB * 640 + lr * 40 + koff];
            if (T + 1 < TC) {
#pragma unroll
                for (int nt = 0; nt < 4; nt++)
                    XN[nt] = *(const float4*)&xz2[((long)(T + 1) * 128 + p0 + nt * 16) * 512 + bq];
            }
            f32x4 acc[4];
#pragma unroll
            for (int nt = 0; nt < 4; nt++) {
                acc[nt] = __builtin_bit_cast(f32x4, XC[nt]);
                acc[nt] = __builtin_amdgcn_mfma_f32_16x16x32_f16(ah, uh[nt], acc[nt], 0, 0, 0);
            }
#pragma unroll
            for (int r = 0; r < 4; r++) {
                float iv = sig_f(acc[0][r]);
                float fv = sig_f(acc[1][r]);
                float gv = th_f(acc[2][r]);
                float ov = sig_f(acc[3][r]);
                cst[r] = fv * cst[r] + iv * gv;
                float h = ov * th_f(cst[r]);
                int rw = (q << 2) + r;
                Ah[(PB ^ 1) * 640 + rw * 40 + cn] = (_Float16)h;
                if (T == TC - 1) {
                    s2h[(long)(b0 + rw) * 32 + cn] = h;
                    s2c[(long)(b0 + rw) * 32 + cn] = cst[r];
                }
            }
        }
        lds_barrier();
    };

    for (int t = 0; t < TC; t += 2) {
        step(t, 0, xc, xn);
        step(t + 1, 1, xn, xc);
    }
}

// ---------------------------------------------------------------------------
// Fused mega kernel: A = lstm1(cA) [WG 0-31], B = lstm2(cB) [WG 32-63],
// C = gemm1(g1) + gemm2(g2) persistent tile loop [remaining WGs].
// ---------------------------------------------------------------------------
__global__ __launch_bounds__(512, 2) void mega(
    const _Float16* __restrict__ xh,
    const _Float16* __restrict__ W1T, const float* __restrict__ b1p,
    const _Float16* __restrict__ W2T, const float* __restrict__ b2p,
    const _Float16* __restrict__ U1p, const _Float16* __restrict__ U2p,
    float* xz1_0, float* xz1_1, float* xz2_0, float* xz2_1,
    _Float16* h1f_0, _Float16* h1f_1,
    float* s1h, float* s1c, float* s2h, float* s2c,
    int cA, int cB, int g1, int g2)
{
    __shared__ __align__(16) char sm[8192];
    int bid = blockIdx.x;

    if (cA >= 0 && bid < 32) {
        const float* xz = (cA & 1) ? xz1_1 : xz1_0;
        _Float16* hf = (cA & 1) ? h1f_1 : h1f_0;
        lstm1_role(xz, U1p, hf, s1h, s1c, cA == 0, sm);
        return;
    }
    if (cB >= 0 && bid >= 32 && bid < 64) {
        const float* xz2 = (cB & 1) ? xz2_1 : xz2_0;
        lstm2_role(xz2, U2p, s2h, s2c, cB == 0, sm);
        return;
    }
    int cwid = bid, ncw = 256;
    if (cA >= 0) { ncw -= 32; cwid -= 32; }
    if (cB >= 0) { ncw -= 32; if (bid >= 64) cwid -= 32; }
    int ng1 = (g1 >= 0) ? 1024 : 0;
    int ng2 = (g2 >= 0) ? 256 : 0;
    float* xz1o = (g1 >= 0 && (g1 & 1)) ? xz1_1 : xz1_0;
    float* xz2o = (g2 >= 0 && (g2 & 1)) ? xz2_1 : xz2_0;
    const _Float16* hf = (g2 >= 0 && (g2 & 1)) ? h1f_1 : h1f_0;
    for (int tile = cwid; tile < ng1 + ng2; tile += ncw) {
        if (tile < ng1)
            gemm_tile<10, true>(xh, W1T, b1p, xz1o, 512,
                                (tile >> 2) * 128, (tile & 3) * 128, g1);
        else
            gemm_tile<4, false>(hf, W2T, b2p, xz2o, 128,
                                (tile - ng1) * 128, 0, 0);
    }
}

// ---------------------------------------------------------------------------
// Head: out = softmax(h2_last @ Wd + bd)   [512,32]@[32,14]
// ---------------------------------------------------------------------------
__global__ __launch_bounds__(256)
void head_kernel(const float* __restrict__ h2, const float* __restrict__ Wd,
                 const float* __restrict__ bd, float* __restrict__ out)
{
    int b = blockIdx.x * 256 + threadIdx.x;
    float h[H2];
#pragma unroll
    for (int k = 0; k < H2; k += 4)
        *(float4*)&h[k] = *(const float4*)&h2[b * H2 + k];

    float lg[NCLS];
#pragma unroll
    for (int c = 0; c < NCLS; c++) lg[c] = bd[c];
#pragma unroll
    for (int k = 0; k < H2; k++) {
        float hv = h[k];
#pragma unroll
        for (int c = 0; c < NCLS; c++)
            lg[c] += hv * Wd[k * NCLS + c];
    }
    float m = lg[0];
#pragma unroll
    for (int c = 1; c < NCLS; c++) m = fmaxf(m, lg[c]);
    float s = 0.f;
#pragma unroll
    for (int c = 0; c < NCLS; c++) { lg[c] = __expf(lg[c] - m); s += lg[c]; }
    float inv = __fdividef(1.0f, s);
#pragma unroll
    for (int c = 0; c < NCLS; c++) out[b * NCLS + c] = lg[c] * inv;
}

// ---------------------------------------------------------------------------
extern "C" void kernel_launch(void* const* d_in, const int* in_sizes, int n_in,
                              void* d_out, int out_size, void* d_ws, size_t ws_size,
                              hipStream_t stream)
{
    const float* x  = (const float*)d_in[0];
    const float* W1 = (const float*)d_in[1];
    const float* U1 = (const float*)d_in[2];
    const float* b1 = (const float*)d_in[3];
    const float* W2 = (const float*)d_in[4];
    const float* U2 = (const float*)d_in[5];
    const float* b2 = (const float*)d_in[6];
    const float* Wd = (const float*)d_in[7];
    const float* bd = (const float*)d_in[8];
    float* out = (float*)d_out;

    char* ws = (char*)d_ws;
    float* xz1[2]  = {(float*)(ws + 0L),         (float*)(ws + 67108864L)};
    _Float16* xh   = (_Float16*)(ws + 134217728L);                 // 167772160
    _Float16* h1f[2] = {(_Float16*)(ws + 301989888L), (_Float16*)(ws + 310378496L)};
    float* xz2[2]  = {(float*)(ws + 318767104L), (float*)(ws + 335544320L)};
    float* s1h     = (float*)(ws + 352321536L);
    float* s1c     = (float*)(ws + 352583680L);
    float* s2h     = (float*)(ws + 352845824L);
    float* s2c     = (float*)(ws + 352911360L);
    _Float16* U1p  = (_Float16*)(ws + 352976896L);
    _Float16* U2p  = (_Float16*)(ws + 353107968L);
    _Float16* W1T  = (_Float16*)(ws + 353116160L);
    _Float16* W2T  = (_Float16*)(ws + 353443840L);
    float* b1p     = (float*)(ws + 353476608L);
    float* b2p     = (float*)(ws + 353478656L);

    prep_weights<<<640, 256, 0, stream>>>(U1, U1p, U2, U2p, W1, W1T, W2, W2T,
                                          b1, b1p, b2, b2p);
    xsplit<<<40960, 256, 0, stream>>>(x, xh);

#define MEGA(cA_, cB_, g1_, g2_) \
    mega<<<256, 512, 0, stream>>>(xh, W1T, b1p, W2T, b2p, U1p, U2p, \
        xz1[0], xz1[1], xz2[0], xz2[1], h1f[0], h1f[1], \
        s1h, s1c, s2h, s2c, cA_, cB_, g1_, g2_)

    MEGA(-1, -1, 0, -1);
    for (int c = 0; c < NC; c++)
        MEGA(c, (c >= 2) ? c - 2 : -1, (c + 1 < NC) ? c + 1 : -1, (c >= 1) ? c - 1 : -1);
    MEGA(-1, NC - 2, -1, NC - 1);
    MEGA(-1, NC - 1, -1, -1);
#undef MEGA

    head_kernel<<<2, 256, 0, stream>>>(s2h, Wd, bd, out);
}

// Round 7
// 1330.578 us; speedup vs baseline: 2.1118x; 1.0617x over previous
//
#include <hip/hip_runtime.h>
#include <math.h>

#define TC 64
#define NC 8
#define BATCH 512
#define T_TOTAL 512
#define D_IN 300
#define KP1 320
#define H1 128
#define G1 512
#define H2 32
#define NCLS 14

typedef unsigned short u16;
typedef __attribute__((ext_vector_type(8))) _Float16 f16x8;
typedef __attribute__((ext_vector_type(4))) float f32x4;

__device__ __forceinline__ float fexp2(float x) { return __builtin_amdgcn_exp2f(x); }
__device__ __forceinline__ float frcp(float x)  { return __builtin_amdgcn_rcpf(x); }
// sigmoid / tanh via exp2 + rcp (4-5 ops each)
__device__ __forceinline__ float sig_f(float x) { return frcp(1.0f + fexp2(-1.44269504f * x)); }
__device__ __forceinline__ float th_f(float x)  { return 1.0f - 2.0f * frcp(1.0f + fexp2(2.88539008f * x)); }

// LDS-only barrier: no vmcnt(0) drain (global loads/stores stay in flight)
__device__ __forceinline__ void lds_barrier() {
    asm volatile("s_waitcnt lgkmcnt(0)" ::: "memory");
    __builtin_amdgcn_s_barrier();
}

// ---------------------------------------------------------------------------
// Prep: permuted-column f16 planes.
// lstm1 perm: p = w*64+nt*16+lr  <->  orig col = nt*128 + w*16 + lr   (w<8)
// lstm2 perm: p = w*64+nt*16+lr  <->  orig col = nt*32  + w*16 + lr   (w<2)
// ---------------------------------------------------------------------------
__global__ void prep_weights(const float* __restrict__ U1, _Float16* __restrict__ U1p,
                             const float* __restrict__ U2, _Float16* __restrict__ U2p,
                             const float* __restrict__ W1, _Float16* __restrict__ W1T,
                             const float* __restrict__ W2, _Float16* __restrict__ W2T,
                             const float* __restrict__ b1, float* __restrict__ b1p,
                             const float* __restrict__ b2, float* __restrict__ b2p)
{
    int idx = blockIdx.x * 256 + threadIdx.x;
    if (idx < 512 * 128) {
        int p = idx >> 7, k = idx & 127;
        int orig = ((p >> 4) & 3) * 128 + ((p >> 6) << 4) + (p & 15);
        U1p[p * 128 + k] = (_Float16)U1[k * 512 + orig];
    }
    if (idx < 512 * 320) {
        int p = idx / 320, k = idx % 320;
        int orig = ((p >> 4) & 3) * 128 + ((p >> 6) << 4) + (p & 15);
        W1T[p * 320 + k] = (_Float16)((k < D_IN) ? W1[k * 512 + orig] : 0.f);
    }
    if (idx < 128 * 128) {
        int p = idx >> 7, k = idx & 127;
        int orig = ((p >> 4) & 3) * 32 + ((p >> 6) << 4) + (p & 15);
        W2T[p * 128 + k] = (_Float16)W2[k * 128 + orig];
    }
    if (idx < 128 * 32) {
        int p = idx >> 5, k = idx & 31;
        int orig = ((p >> 4) & 3) * 32 + ((p >> 6) << 4) + (p & 15);
        U2p[p * 32 + k] = (_Float16)U2[k * 128 + orig];
    }
    if (idx < 512) {
        int orig = ((idx >> 4) & 3) * 128 + ((idx >> 6) << 4) + (idx & 15);
        b1p[idx] = b1[orig];
    }
    if (idx < 128) {
        int orig = ((idx >> 4) & 3) * 32 + ((idx >> 6) << 4) + (idx & 15);
        b2p[idx] = b2[orig];
    }
}

// ---------------------------------------------------------------------------
// x [B*T][300] f32 -> f16 plane [B*T][320]; vectorized: 8 floats/thread via
// 2x float4 (row stride 1200 B and k0*4 are 16B-aligned); tail handled by
// branch on segment index only (s=37 partial, s>=38 pure pad).
// ---------------------------------------------------------------------------
__global__ void xsplit(const float* __restrict__ x, _Float16* __restrict__ xh)
{
    long gid = (long)blockIdx.x * 256 + threadIdx.x;
    if (gid >= 262144L * 40) return;
    int m  = (int)(gid / 40);
    int s  = (int)(gid % 40);
    int k0 = s * 8;
    const float* xr = x + (long)m * D_IN + k0;
    float4 v0 = {0.f, 0.f, 0.f, 0.f}, v1 = {0.f, 0.f, 0.f, 0.f};
    if (s < 37) {                 // k0+7 <= 295: both vectors in-bounds
        v0 = *(const float4*)(xr);
        v1 = *(const float4*)(xr + 4);
    } else if (s == 37) {         // 296..299 valid, 300..303 pad
        v0 = *(const float4*)(xr);
    }
    f16x8 o;
    o[0] = (_Float16)v0.x; o[1] = (_Float16)v0.y;
    o[2] = (_Float16)v0.z; o[3] = (_Float16)v0.w;
    o[4] = (_Float16)v1.x; o[5] = (_Float16)v1.y;
    o[6] = (_Float16)v1.z; o[7] = (_Float16)v1.w;
    *(f16x8*)(xh + (long)m * KP1 + k0) = o;
}

// ---------------------------------------------------------------------------
// Frag-direct f16 GEMM tile (128x128), 8 waves (2x4), wave = 64x32.
// M-index m <-> (b,t): b = ((m>>8)<<2)|(m&3), t = (m>>2)&63.
// C layout: [t][Nc][512b]. A row: XMAP ? b*512+chunk*64+t : b*64+t.
// ---------------------------------------------------------------------------
template<int NK, bool XMAP>
__device__ __forceinline__ void gemm_tile(
    const _Float16* __restrict__ A, const _Float16* __restrict__ B,
    const float* __restrict__ bias, float* __restrict__ C,
    int Nc, int m0, int n0, int chunk)
{
    const int tid = threadIdx.x;
    const int l = tid & 63, w = tid >> 6;
    const int wm = w >> 2, wn = w & 3;
    const int lr = l & 15, q = l >> 4;
    const int koff = q * 8;
    const int LDA = NK * 32;

    const _Float16* ap[4];
#pragma unroll
    for (int fi = 0; fi < 4; fi++) {
        int m = m0 + wm * 64 + fi * 16 + lr;
        int b = ((m >> 8) << 2) | (m & 3);
        int t = (m >> 2) & 63;
        long row = XMAP ? ((long)b * T_TOTAL + (long)chunk * TC + t)
                        : ((long)b * TC + t);
        ap[fi] = A + row * LDA + koff;
    }
    const _Float16* bp[2];
    float bv[2];
#pragma unroll
    for (int fj = 0; fj < 2; fj++) {
        int nc = n0 + wn * 32 + fj * 16 + lr;
        bp[fj] = B + (long)nc * LDA + koff;
        bv[fj] = bias[nc];
    }
    f32x4 acc[4][2];
#pragma unroll
    for (int fi = 0; fi < 4; fi++)
#pragma unroll
        for (int fj = 0; fj < 2; fj++)
            acc[fi][fj] = (f32x4){bv[fj], bv[fj], bv[fj], bv[fj]};

#pragma unroll
    for (int ks = 0; ks < NK; ks++) {
        f16x8 av[4], bvv[2];
#pragma unroll
        for (int fj = 0; fj < 2; fj++)
            bvv[fj] = *(const f16x8*)(bp[fj] + ks * 32);
#pragma unroll
        for (int fi = 0; fi < 4; fi++)
            av[fi] = *(const f16x8*)(ap[fi] + ks * 32);
#pragma unroll
        for (int fi = 0; fi < 4; fi++)
#pragma unroll
            for (int fj = 0; fj < 2; fj++)
                acc[fi][fj] = __builtin_amdgcn_mfma_f32_16x16x32_f16(av[fi], bvv[fj], acc[fi][fj], 0, 0, 0);
    }

#pragma unroll
    for (int fi = 0; fi < 4; fi++) {
        int mq = m0 + wm * 64 + fi * 16 + q * 4;
        int bb = (mq >> 8) << 2;
        int tt = (mq >> 2) & 63;
#pragma unroll
        for (int fj = 0; fj < 2; fj++) {
            int col = n0 + wn * 32 + fj * 16 + lr;
            *(float4*)(C + ((long)tt * Nc + col) * 512 + bb) =
                *(float4*)&acc[fi][fj];
        }
    }
}

// ---------------------------------------------------------------------------
// Role A: lstm1 scan, f16 single-product. WG owns 16 batch rows; wave w owns
// the 4 gates of h-cols w*16..w*16+15 (permuted layout). In-register c/h
// update; 1 LDS-only barrier/step; dbuf XOR-swizzled f16 h tile.
// xz layout [t][512p][512b] -> 4 float4 loads/step that ARE the MFMA C-init.
// ---------------------------------------------------------------------------
static __device__ __forceinline__ void lstm1_role(
    const float* __restrict__ xz, const _Float16* __restrict__ U1p,
    _Float16* __restrict__ h1f, float* __restrict__ s1h, float* __restrict__ s1c,
    int first, char* smc)
{
    const int tid = threadIdx.x;
    const int l = tid & 63, w = tid >> 6;
    const int lr = l & 15, q = l >> 4;
    const int koff = q * 8;
    const int cn = w * 16 + lr;
    const int b0 = blockIdx.x * 16;
    const int p0 = w * 64 + lr;
    const int bq = b0 + q * 4;

    _Float16* Ah = (_Float16*)smc;   // [2][16][128]

    f16x8 uh[4][4];
#pragma unroll
    for (int nt = 0; nt < 4; nt++)
#pragma unroll
        for (int kt = 0; kt < 4; kt++)
            uh[nt][kt] = *(const f16x8*)(U1p + (long)(w * 64 + nt * 16 + lr) * 128 + kt * 32 + koff);

    float cst[4];
#pragma unroll
    for (int r = 0; r < 4; r++) {
        int rw = q * 4 + r;
        float h = 0.f;
        cst[r] = 0.f;
        if (!first) {
            h = s1h[(long)(b0 + rw) * 128 + cn];
            cst[r] = s1c[(long)(b0 + rw) * 128 + cn];
        }
        int idx = (((cn >> 3) ^ rw) << 3) + (cn & 7);
        Ah[rw * 128 + idx] = (_Float16)h;
    }
    lds_barrier();

    float4 xc[4], xn[4];
#pragma unroll
    for (int nt = 0; nt < 4; nt++)
        xc[nt] = *(const float4*)&xz[((long)0 * 512 + p0 + nt * 16) * 512 + bq];

    auto step = [&](int T, int PB, float4* XC, float4* XN) {
        f16x8 ah[4];
#pragma unroll
        for (int kt = 0; kt < 4; kt++)
            ah[kt] = *(const f16x8*)&Ah[PB * 2048 + lr * 128 + ((((kt << 2) + q) ^ lr) << 3)];
        if (T + 1 < TC) {
#pragma unroll
            for (int nt = 0; nt < 4; nt++)
                XN[nt] = *(const float4*)&xz[((long)(T + 1) * 512 + p0 + nt * 16) * 512 + bq];
        }
        f32x4 acc[4];
#pragma unroll
        for (int nt = 0; nt < 4; nt++)
            acc[nt] = __builtin_bit_cast(f32x4, XC[nt]);
#pragma unroll
        for (int kt = 0; kt < 4; kt++)
#pragma unroll
            for (int nt = 0; nt < 4; nt++)
                acc[nt] = __builtin_amdgcn_mfma_f32_16x16x32_f16(ah[kt], uh[nt][kt], acc[nt], 0, 0, 0);
#pragma unroll
        for (int r = 0; r < 4; r++) {
            float iv = sig_f(acc[0][r]);
            float fv = sig_f(acc[1][r]);
            float gv = th_f(acc[2][r]);
            float ov = sig_f(acc[3][r]);
            cst[r] = fv * cst[r] + iv * gv;
            float h = ov * th_f(cst[r]);
            _Float16 hh = (_Float16)h;
            int rw = (q << 2) + r;
            int idx = (((cn >> 3) ^ rw) << 3) + (cn & 7);
            Ah[(PB ^ 1) * 2048 + rw * 128 + idx] = hh;
            h1f[((long)(b0 + rw) * TC + T) * 128 + cn] = hh;
            if (T == TC - 1) {
                s1h[(long)(b0 + rw) * 128 + cn] = h;
                s1c[(long)(b0 + rw) * 128 + cn] = cst[r];
            }
        }
        lds_barrier();
    };

    for (int t = 0; t < TC; t += 2) {
        step(t, 0, xc, xn);
        step(t + 1, 1, xn, xc);
    }
}

// ---------------------------------------------------------------------------
// Role B: lstm2 scan, f16 single-product, waves 0-1 active.
// xz2 layout [t][128p][512b].
// ---------------------------------------------------------------------------
static __device__ __forceinline__ void lstm2_role(
    const float* __restrict__ xz2, const _Float16* __restrict__ U2p,
    float* __restrict__ s2h, float* __restrict__ s2c, int first, char* smc)
{
    const int tid = threadIdx.x;
    const int b0 = (blockIdx.x - 32) * 16;
    const bool act = tid < 128;
    const int l = tid & 63, w = (tid >> 6) & 1;
    const int lr = l & 15, q = l >> 4;
    const int koff = q * 8;
    const int cn = w * 16 + lr;
    const int p0 = w * 64 + lr;
    const int bq = b0 + q * 4;

    _Float16* Ah = (_Float16*)smc;   // [2][16][40]

    f16x8 uh[4];
    float cst[4] = {0.f, 0.f, 0.f, 0.f};
    float4 xc[4], xn[4];

    if (act) {
#pragma unroll
        for (int nt = 0; nt < 4; nt++)
            uh[nt] = *(const f16x8*)(U2p + (long)(w * 64 + nt * 16 + lr) * 32 + koff);
#pragma unroll
        for (int r = 0; r < 4; r++) {
            int rw = q * 4 + r;
            float h = 0.f;
            if (!first) {
                h = s2h[(long)(b0 + rw) * 32 + cn];
                cst[r] = s2c[(long)(b0 + rw) * 32 + cn];
            }
            Ah[rw * 40 + cn] = (_Float16)h;
        }
#pragma unroll
        for (int nt = 0; nt < 4; nt++)
            xc[nt] = *(const float4*)&xz2[((long)0 * 128 + p0 + nt * 16) * 512 + bq];
    }
    lds_barrier();

    auto step = [&](int T, int PB, float4* XC, float4* XN) {
        if (act) {
            f16x8 ah = *(const f16x8*)&Ah[PB * 640 + lr * 40 + koff];
            if (T + 1 < TC) {
#pragma unroll
                for (int nt = 0; nt < 4; nt++)
                    XN[nt] = *(const float4*)&xz2[((long)(T + 1) * 128 + p0 + nt * 16) * 512 + bq];
            }
            f32x4 acc[4];
#pragma unroll
            for (int nt = 0; nt < 4; nt++) {
                acc[nt] = __builtin_bit_cast(f32x4, XC[nt]);
                acc[nt] = __builtin_amdgcn_mfma_f32_16x16x32_f16(ah, uh[nt], acc[nt], 0, 0, 0);
            }
#pragma unroll
            for (int r = 0; r < 4; r++) {
                float iv = sig_f(acc[0][r]);
                float fv = sig_f(acc[1][r]);
                float gv = th_f(acc[2][r]);
                float ov = sig_f(acc[3][r]);
                cst[r] = fv * cst[r] + iv * gv;
                float h = ov * th_f(cst[r]);
                int rw = (q << 2) + r;
                Ah[(PB ^ 1) * 640 + rw * 40 + cn] = (_Float16)h;
                if (T == TC - 1) {
                    s2h[(long)(b0 + rw) * 32 + cn] = h;
                    s2c[(long)(b0 + rw) * 32 + cn] = cst[r];
                }
            }
        }
        lds_barrier();
    };

    for (int t = 0; t < TC; t += 2) {
        step(t, 0, xc, xn);
        step(t + 1, 1, xn, xc);
    }
}

// ---------------------------------------------------------------------------
// Fused mega kernel: A = lstm1(cA) [WG 0-31], B = lstm2(cB) [WG 32-63],
// C = gemm1(g1) + gemm2(g2) persistent tile loop [remaining WGs].
// launch_bounds(512,1): grid is 256 WGs = 1/CU, so claim the full 256-VGPR
// budget (2 waves/SIMD) — (512,2) capped at 128 VGPR and spilled lstm1.
// ---------------------------------------------------------------------------
__global__ __launch_bounds__(512, 1) void mega(
    const _Float16* __restrict__ xh,
    const _Float16* __restrict__ W1T, const float* __restrict__ b1p,
    const _Float16* __restrict__ W2T, const float* __restrict__ b2p,
    const _Float16* __restrict__ U1p, const _Float16* __restrict__ U2p,
    float* xz1_0, float* xz1_1, float* xz2_0, float* xz2_1,
    _Float16* h1f_0, _Float16* h1f_1,
    float* s1h, float* s1c, float* s2h, float* s2c,
    int cA, int cB, int g1, int g2)
{
    __shared__ __align__(16) char sm[8192];
    int bid = blockIdx.x;

    if (cA >= 0 && bid < 32) {
        const float* xz = (cA & 1) ? xz1_1 : xz1_0;
        _Float16* hf = (cA & 1) ? h1f_1 : h1f_0;
        lstm1_role(xz, U1p, hf, s1h, s1c, cA == 0, sm);
        return;
    }
    if (cB >= 0 && bid >= 32 && bid < 64) {
        const float* xz2 = (cB & 1) ? xz2_1 : xz2_0;
        lstm2_role(xz2, U2p, s2h, s2c, cB == 0, sm);
        return;
    }
    int cwid = bid, ncw = 256;
    if (cA >= 0) { ncw -= 32; cwid -= 32; }
    if (cB >= 0) { ncw -= 32; if (bid >= 64) cwid -= 32; }
    int ng1 = (g1 >= 0) ? 1024 : 0;
    int ng2 = (g2 >= 0) ? 256 : 0;
    float* xz1o = (g1 >= 0 && (g1 & 1)) ? xz1_1 : xz1_0;
    float* xz2o = (g2 >= 0 && (g2 & 1)) ? xz2_1 : xz2_0;
    const _Float16* hf = (g2 >= 0 && (g2 & 1)) ? h1f_1 : h1f_0;
    for (int tile = cwid; tile < ng1 + ng2; tile += ncw) {
        if (tile < ng1)
            gemm_tile<10, true>(xh, W1T, b1p, xz1o, 512,
                                (tile >> 2) * 128, (tile & 3) * 128, g1);
        else
            gemm_tile<4, false>(hf, W2T, b2p, xz2o, 128,
                                (tile - ng1) * 128, 0, 0);
    }
}

// ---------------------------------------------------------------------------
// Head: out = softmax(h2_last @ Wd + bd)   [512,32]@[32,14]
// ---------------------------------------------------------------------------
__global__ __launch_bounds__(256)
void head_kernel(const float* __restrict__ h2, const float* __restrict__ Wd,
                 const float* __restrict__ bd, float* __restrict__ out)
{
    int b = blockIdx.x * 256 + threadIdx.x;
    float h[H2];
#pragma unroll
    for (int k = 0; k < H2; k += 4)
        *(float4*)&h[k] = *(const float4*)&h2[b * H2 + k];

    float lg[NCLS];
#pragma unroll
    for (int c = 0; c < NCLS; c++) lg[c] = bd[c];
#pragma unroll
    for (int k = 0; k < H2; k++) {
        float hv = h[k];
#pragma unroll
        for (int c = 0; c < NCLS; c++)
            lg[c] += hv * Wd[k * NCLS + c];
    }
    float m = lg[0];
#pragma unroll
    for (int c = 1; c < NCLS; c++) m = fmaxf(m, lg[c]);
    float s = 0.f;
#pragma unroll
    for (int c = 0; c < NCLS; c++) { lg[c] = __expf(lg[c] - m); s += lg[c]; }
    float inv = __fdividef(1.0f, s);
#pragma unroll
    for (int c = 0; c < NCLS; c++) out[b * NCLS + c] = lg[c] * inv;
}

// ---------------------------------------------------------------------------
extern "C" void kernel_launch(void* const* d_in, const int* in_sizes, int n_in,
                              void* d_out, int out_size, void* d_ws, size_t ws_size,
                              hipStream_t stream)
{
    const float* x  = (const float*)d_in[0];
    const float* W1 = (const float*)d_in[1];
    const float* U1 = (const float*)d_in[2];
    const float* b1 = (const float*)d_in[3];
    const float* W2 = (const float*)d_in[4];
    const float* U2 = (const float*)d_in[5];
    const float* b2 = (const float*)d_in[6];
    const float* Wd = (const float*)d_in[7];
    const float* bd = (const float*)d_in[8];
    float* out = (float*)d_out;

    char* ws = (char*)d_ws;
    float* xz1[2]  = {(float*)(ws + 0L),         (float*)(ws + 67108864L)};
    _Float16* xh   = (_Float16*)(ws + 134217728L);                 // 167772160
    _Float16* h1f[2] = {(_Float16*)(ws + 301989888L), (_Float16*)(ws + 310378496L)};
    float* xz2[2]  = {(float*)(ws + 318767104L), (float*)(ws + 335544320L)};
    float* s1h     = (float*)(ws + 352321536L);
    float* s1c     = (float*)(ws + 352583680L);
    float* s2h     = (float*)(ws + 352845824L);
    float* s2c     = (float*)(ws + 352911360L);
    _Float16* U1p  = (_Float16*)(ws + 352976896L);
    _Float16* U2p  = (_Float16*)(ws + 353107968L);
    _Float16* W1T  = (_Float16*)(ws + 353116160L);
    _Float16* W2T  = (_Float16*)(ws + 353443840L);
    float* b1p     = (float*)(ws + 353476608L);
    float* b2p     = (float*)(ws + 353478656L);

    prep_weights<<<640, 256, 0, stream>>>(U1, U1p, U2, U2p, W1, W1T, W2, W2T,
                                          b1, b1p, b2, b2p);
    xsplit<<<40960, 256, 0, stream>>>(x, xh);

#define MEGA(cA_, cB_, g1_, g2_) \
    mega<<<256, 512, 0, stream>>>(xh, W1T, b1p, W2T, b2p, U1p, U2p, \
        xz1[0], xz1[1], xz2[0], xz2[1], h1f[0], h1f[1], \
        s1h, s1c, s2h, s2c, cA_, cB_, g1_, g2_)

    MEGA(-1, -1, 0, -1);
    for (int c = 0; c < NC; c++)
        MEGA(c, (c >= 2) ? c - 2 : -1, (c + 1 < NC) ? c + 1 : -1, (c >= 1) ? c - 1 : -1);
    MEGA(-1, NC - 2, -1, NC - 1);
    MEGA(-1, NC - 1, -1, -1);
#undef MEGA

    head_kernel<<<2, 256, 0, stream>>>(s2h, Wd, bd, out);
}